// Round 1
// baseline (330.402 us; speedup 1.0000x reference)
//
#include <hip/hip_runtime.h>
#include <hip/hip_bf16.h>
#include <stdint.h>

#define GAT_ALPHA 0.2f
#define LOG2E 1.4426950408889634f

typedef __attribute__((ext_vector_type(8))) __bf16 bf16x8;
typedef __attribute__((ext_vector_type(4))) float f32x4;

union B8 {
  bf16x8 b;
  unsigned short u[8];
  int4 i4;
};

__device__ __forceinline__ unsigned short f2bf(float f) {
  unsigned int u = __float_as_uint(f);
  u += 0x7fffu + ((u >> 16) & 1u);   // RNE; inputs are finite, no NaN handling needed
  return (unsigned short)(u >> 16);
}

// ---------------- Kernel A: wh = x @ W^T (fp32), emit whT (bf16, o-major), s, d ----
// 32 rows/block, 256 threads. Thread: 4 o's (lane32 + 32m) x 4 rows ((tid/32)*4+r).
__global__ __launch_bounds__(256) void gat_wh(
    const float* __restrict__ x, const float* __restrict__ W,
    const float* __restrict__ a, unsigned short* __restrict__ whT,
    float* __restrict__ s_out, float* __restrict__ d_out) {
  __shared__ float X[32][260];               // +4 pad: 2-way max bank conflict, keeps 16B align
  const int tid = threadIdx.x;
  const int row0 = blockIdx.x * 32;          // flat row in [0,16384)
  {
    const int rr = tid >> 3;                 // 0..31
    const int seg = (tid & 7) << 2;          // 0..28
    const float* xrow = x + (size_t)(row0 + rr) * 256;
#pragma unroll
    for (int it = 0; it < 8; ++it) {
      const int k = seg + it * 32;
      *(float4*)(&X[rr][k]) = *(const float4*)(xrow + k);
    }
  }
  __syncthreads();
  const int lane32 = tid & 31;
  const int r0 = (tid >> 5) << 2;
  float acc[4][4];                           // [m (o-group)][r (row)]
#pragma unroll
  for (int m = 0; m < 4; ++m)
#pragma unroll
    for (int r = 0; r < 4; ++r) acc[m][r] = 0.f;
  const float* W0 = W + (size_t)lane32 * 256;
#pragma unroll 2
  for (int k = 0; k < 256; k += 4) {
    float4 xv[4], wv[4];
#pragma unroll
    for (int r = 0; r < 4; ++r) xv[r] = *(const float4*)(&X[r0 + r][k]);
#pragma unroll
    for (int m = 0; m < 4; ++m) wv[m] = *(const float4*)(W0 + (size_t)m * (32 * 256) + k);
#pragma unroll
    for (int m = 0; m < 4; ++m)
#pragma unroll
      for (int r = 0; r < 4; ++r) {
        acc[m][r] = fmaf(wv[m].x, xv[r].x, acc[m][r]);
        acc[m][r] = fmaf(wv[m].y, xv[r].y, acc[m][r]);
        acc[m][r] = fmaf(wv[m].z, xv[r].z, acc[m][r]);
        acc[m][r] = fmaf(wv[m].w, xv[r].w, acc[m][r]);
      }
  }
  // s = wh . a_src, d = wh . a_dst : partials over this thread's 4 o's, reduce over 32 lanes
  float asrc[4], adst[4];
#pragma unroll
  for (int m = 0; m < 4; ++m) {
    asrc[m] = a[lane32 + 32 * m];
    adst[m] = a[128 + lane32 + 32 * m];
  }
  float sp[4], dp[4];
#pragma unroll
  for (int r = 0; r < 4; ++r) {
    sp[r] = acc[0][r] * asrc[0] + acc[1][r] * asrc[1] + acc[2][r] * asrc[2] + acc[3][r] * asrc[3];
    dp[r] = acc[0][r] * adst[0] + acc[1][r] * adst[1] + acc[2][r] * adst[2] + acc[3][r] * adst[3];
  }
#pragma unroll
  for (int off = 16; off >= 1; off >>= 1) {
#pragma unroll
    for (int r = 0; r < 4; ++r) {
      sp[r] += __shfl_xor(sp[r], off, 64);
      dp[r] += __shfl_xor(dp[r], off, 64);
    }
  }
  if (lane32 == 0) {
#pragma unroll
    for (int r = 0; r < 4; ++r) {
      s_out[row0 + r0 + r] = sp[r];
      d_out[row0 + r0 + r] = dp[r];
    }
  }
  // whT[b][o][row_in_batch] bf16 — thread writes 4 consecutive rows per o (8B store)
  const int b = row0 >> 11;
  const int rib = (row0 & 2047) + r0;
#pragma unroll
  for (int m = 0; m < 4; ++m) {
    const int o = lane32 + 32 * m;
    uint2 pk;
    pk.x = (unsigned int)f2bf(acc[m][0]) | ((unsigned int)f2bf(acc[m][1]) << 16);
    pk.y = (unsigned int)f2bf(acc[m][2]) | ((unsigned int)f2bf(acc[m][3]) << 16);
    *(uint2*)(whT + (((size_t)(b * 128 + o)) << 11) + rib) = pk;
  }
}

// ---------------- Kernel B: flash-style masked attention via MFMA --------------------
// out^T tile = V^T (A-operand, from whT) x P^T (B-operand, computed in-register).
// Block = 128 thr = 2 waves; wave handles 16 rows i; j-loop in chunks of 32.
__global__ __launch_bounds__(128) void gat_attn(
    const int* __restrict__ adj, const unsigned short* __restrict__ whT,
    const float* __restrict__ s, const float* __restrict__ dvec,
    float* __restrict__ out) {
  __shared__ float dl[2048];
  const int tid = threadIdx.x;
  const int blk = blockIdx.x;
  const int b = blk >> 6;
  const int tile = blk & 63;
  {
    const float* dsrc = dvec + ((size_t)b << 11);
#pragma unroll
    for (int it = 0; it < 4; ++it) {
      const int idx = it * 512 + tid * 4;
      *(float4*)(&dl[idx]) = *(const float4*)(dsrc + idx);
    }
  }
  __syncthreads();
  const int lane = tid & 63;
  const int wave = tid >> 6;
  const int il = lane & 15;     // MFMA n-index -> row i ; also m-index -> o
  const int quad = lane >> 4;   // k-chunk selector
  const int qo = quad << 3;
  const int i = tile * 32 + wave * 16 + il;
  const size_t browi = ((size_t)b << 11) + i;
  const float sv = s[browi];
  const int* adjq = adj + browi * 2048 + qo;
  const unsigned short* whTb = whT + (((size_t)b * 128) << 11);
  const unsigned short* wrow[8];
#pragma unroll
  for (int nt = 0; nt < 8; ++nt)
    wrow[nt] = whTb + (((size_t)(nt * 16 + il)) << 11) + qo;

  f32x4 acc[8];
#pragma unroll
  for (int nt = 0; nt < 8; ++nt) acc[nt] = (f32x4){0.f, 0.f, 0.f, 0.f};
  float den = 0.f;

  int4 adjbuf[2][2];            // 2-deep prefetch of adj (8 ints per lane per iter)
  adjbuf[0][0] = *(const int4*)(adjq);
  adjbuf[0][1] = *(const int4*)(adjq + 4);
  adjbuf[1][0] = *(const int4*)(adjq + 32);
  adjbuf[1][1] = *(const int4*)(adjq + 36);

#pragma unroll 2
  for (int t = 0; t < 64; ++t) {
    const int j0 = t * 32;
    B8 af[8];                   // A-frags: V^T[o=nt*16+il][j0+qo .. +7], contiguous 16B
#pragma unroll
    for (int nt = 0; nt < 8; ++nt) af[nt].i4 = *(const int4*)(wrow[nt] + j0);
    const int4 aj0 = adjbuf[t & 1][0];
    const int4 aj1 = adjbuf[t & 1][1];
    if (t < 62) {
      adjbuf[t & 1][0] = *(const int4*)(adjq + (t + 2) * 32);
      adjbuf[t & 1][1] = *(const int4*)(adjq + (t + 2) * 32 + 4);
    }
    const float4 d0 = *(const float4*)(&dl[j0 + qo]);
    const float4 d1 = *(const float4*)(&dl[j0 + qo + 4]);
    const float dd[8] = {d0.x, d0.y, d0.z, d0.w, d1.x, d1.y, d1.z, d1.w};
    const int aj[8] = {aj0.x, aj0.y, aj0.z, aj0.w, aj1.x, aj1.y, aj1.z, aj1.w};
    B8 pf;                      // B-frag: P^T[k=j][n=i] == this lane's p for 8 j's
#pragma unroll
    for (int u = 0; u < 8; ++u) {
      float e = sv + dd[u];
      e = fmaxf(e, GAT_ALPHA * e);              // leaky relu
      float p = __builtin_amdgcn_exp2f(e * LOG2E);  // no max-sub needed: e <= ~18
      p = (aj[u] != 0) ? p : 0.f;
      den += p;
      pf.u[u] = f2bf(p);
    }
#pragma unroll
    for (int nt = 0; nt < 8; ++nt)
      acc[nt] = __builtin_amdgcn_mfma_f32_16x16x32_bf16(af[nt].b, pf.b, acc[nt], 0, 0, 0);
  }
  // den partials live on lanes {il, il+16, il+32, il+48} (quads 0..3)
  den += __shfl_xor(den, 16, 64);
  den += __shfl_xor(den, 32, 64);
  const float inv = 1.0f / den;
  // D layout: col = lane&15 = i, row = 4*quad + reg = o within nt-tile (consecutive o!)
  float* op = out + browi * 128;
#pragma unroll
  for (int nt = 0; nt < 8; ++nt) {
    float4 v;
    v.x = fmaxf(acc[nt][0] * inv, 0.f);
    v.y = fmaxf(acc[nt][1] * inv, 0.f);
    v.z = fmaxf(acc[nt][2] * inv, 0.f);
    v.w = fmaxf(acc[nt][3] * inv, 0.f);
    *(float4*)(op + nt * 16 + quad * 4) = v;
  }
}

extern "C" void kernel_launch(void* const* d_in, const int* in_sizes, int n_in,
                              void* d_out, int out_size, void* d_ws, size_t ws_size,
                              hipStream_t stream) {
  const float* x = (const float*)d_in[0];
  const int* adj = (const int*)d_in[1];
  const float* W = (const float*)d_in[2];
  const float* a = (const float*)d_in[3];
  float* out = (float*)d_out;
  // workspace: whT bf16 [8][128][2048] (4 MB) | s fp32 [16384] | d fp32 [16384]
  unsigned short* whT = (unsigned short*)d_ws;
  float* s = (float*)((char*)d_ws + (size_t)8 * 128 * 2048 * 2);
  float* dv = s + 16384;
  gat_wh<<<512, 256, 0, stream>>>(x, W, a, whT, s, dv);
  gat_attn<<<512, 128, 0, stream>>>(adj, whT, s, dv, out);
}

// Round 2
// 317.556 us; speedup vs baseline: 1.0405x; 1.0405x over previous
//
#include <hip/hip_runtime.h>
#include <hip/hip_bf16.h>
#include <stdint.h>

#define GAT_ALPHA 0.2f
#define LOG2E 1.4426950408889634f

typedef __attribute__((ext_vector_type(8))) __bf16 bf16x8;
typedef __attribute__((ext_vector_type(4))) float f32x4;

union B8 {
  bf16x8 b;
  unsigned short u[8];
  int4 i4;
};

__device__ __forceinline__ unsigned short f2bf(float f) {
  unsigned int u = __float_as_uint(f);
  u += 0x7fffu + ((u >> 16) & 1u);   // RNE; inputs are finite
  return (unsigned short)(u >> 16);
}

// ---------------- Kernel A: wh = x @ W^T (fp32), emit whT (bf16, o-major), s, d ----
// 32 rows/block, 256 threads. Thread: 4 o's (lane32 + 32m) x 4 rows ((tid/32)*4+r).
__global__ __launch_bounds__(256) void gat_wh(
    const float* __restrict__ x, const float* __restrict__ W,
    const float* __restrict__ a, unsigned short* __restrict__ whT,
    float* __restrict__ s_out, float* __restrict__ d_out) {
  __shared__ float X[32][260];               // +4 pad keeps 16B align, 2-way max conflict
  const int tid = threadIdx.x;
  const int row0 = blockIdx.x * 32;          // flat row in [0,16384)
  {
    const int rr = tid >> 3;                 // 0..31
    const int seg = (tid & 7) << 2;          // 0..28
    const float* xrow = x + (size_t)(row0 + rr) * 256;
#pragma unroll
    for (int it = 0; it < 8; ++it) {
      const int k = seg + it * 32;
      *(float4*)(&X[rr][k]) = *(const float4*)(xrow + k);
    }
  }
  __syncthreads();
  const int lane32 = tid & 31;
  const int r0 = (tid >> 5) << 2;
  float acc[4][4];                           // [m (o-group)][r (row)]
#pragma unroll
  for (int m = 0; m < 4; ++m)
#pragma unroll
    for (int r = 0; r < 4; ++r) acc[m][r] = 0.f;
  const float* W0 = W + (size_t)lane32 * 256;
#pragma unroll 2
  for (int k = 0; k < 256; k += 4) {
    float4 xv[4], wv[4];
#pragma unroll
    for (int r = 0; r < 4; ++r) xv[r] = *(const float4*)(&X[r0 + r][k]);
#pragma unroll
    for (int m = 0; m < 4; ++m) wv[m] = *(const float4*)(W0 + (size_t)m * (32 * 256) + k);
#pragma unroll
    for (int m = 0; m < 4; ++m)
#pragma unroll
      for (int r = 0; r < 4; ++r) {
        acc[m][r] = fmaf(wv[m].x, xv[r].x, acc[m][r]);
        acc[m][r] = fmaf(wv[m].y, xv[r].y, acc[m][r]);
        acc[m][r] = fmaf(wv[m].z, xv[r].z, acc[m][r]);
        acc[m][r] = fmaf(wv[m].w, xv[r].w, acc[m][r]);
      }
  }
  float asrc[4], adst[4];
#pragma unroll
  for (int m = 0; m < 4; ++m) {
    asrc[m] = a[lane32 + 32 * m];
    adst[m] = a[128 + lane32 + 32 * m];
  }
  float sp[4], dp[4];
#pragma unroll
  for (int r = 0; r < 4; ++r) {
    sp[r] = acc[0][r] * asrc[0] + acc[1][r] * asrc[1] + acc[2][r] * asrc[2] + acc[3][r] * asrc[3];
    dp[r] = acc[0][r] * adst[0] + acc[1][r] * adst[1] + acc[2][r] * adst[2] + acc[3][r] * adst[3];
  }
#pragma unroll
  for (int off = 16; off >= 1; off >>= 1) {
#pragma unroll
    for (int r = 0; r < 4; ++r) {
      sp[r] += __shfl_xor(sp[r], off, 64);
      dp[r] += __shfl_xor(dp[r], off, 64);
    }
  }
  if (lane32 == 0) {
#pragma unroll
    for (int r = 0; r < 4; ++r) {
      s_out[row0 + r0 + r] = sp[r];
      d_out[row0 + r0 + r] = dp[r];
    }
  }
  const int b = row0 >> 11;
  const int rib = (row0 & 2047) + r0;
#pragma unroll
  for (int m = 0; m < 4; ++m) {
    const int o = lane32 + 32 * m;
    uint2 pk;
    pk.x = (unsigned int)f2bf(acc[m][0]) | ((unsigned int)f2bf(acc[m][1]) << 16);
    pk.y = (unsigned int)f2bf(acc[m][2]) | ((unsigned int)f2bf(acc[m][3]) << 16);
    *(uint2*)(whT + (((size_t)(b * 128 + o)) << 11) + rib) = pk;
  }
}

// ---------------- Kernel B: masked attention via MFMA, j-split 4x for occupancy ----
// Block = 256 thr = 4 waves. Block owns 16 rows i; wave w handles j in [w*512,(w+1)*512).
// Partial num (acc) and den combined through LDS. Softmax has no running max
// (e <= ~18, exp in fp32 never overflows) so the j-split is a plain linear sum.
__global__ __launch_bounds__(256) void gat_attn(
    const int* __restrict__ adj, const unsigned short* __restrict__ whT,
    const float* __restrict__ s, const float* __restrict__ dvec,
    float* __restrict__ out) {
  __shared__ float buf[4][16][132];    // [wave][i][o] fp32 partial num, pitch 132
  __shared__ float denb[64];           // [wave][i] partial den
  const int tid = threadIdx.x;
  const int wave = tid >> 6;
  const int lane = tid & 63;
  const int il = lane & 15;     // MFMA n-index -> row i ; also m-index col in D
  const int quad = lane >> 4;
  const int qo = quad << 3;
  const int blk = blockIdx.x;
  const int b = blk >> 7;
  const int tile = blk & 127;
  const int i = tile * 16 + il;
  const size_t browi = ((size_t)b << 11) + i;
  const float sv = s[browi];
  const int jb = wave << 9;            // wave's j-segment base
  const int* adjq = adj + browi * 2048 + jb + qo;
  const float* dptr = dvec + ((size_t)b << 11) + jb + qo;
  const unsigned short* whTb = whT + (((size_t)b * 128) << 11);
  const unsigned short* wrow[8];
#pragma unroll
  for (int nt = 0; nt < 8; ++nt)
    wrow[nt] = whTb + (((size_t)(nt * 16 + il)) << 11) + jb + qo;

  f32x4 acc[8];
#pragma unroll
  for (int nt = 0; nt < 8; ++nt) acc[nt] = (f32x4){0.f, 0.f, 0.f, 0.f};
  float den = 0.f;

  int4 adjbuf[2][2];            // 2-deep prefetch of adj (8 ints per lane per iter)
  adjbuf[0][0] = *(const int4*)(adjq);
  adjbuf[0][1] = *(const int4*)(adjq + 4);
  adjbuf[1][0] = *(const int4*)(adjq + 32);
  adjbuf[1][1] = *(const int4*)(adjq + 36);

#pragma unroll 2
  for (int t = 0; t < 16; ++t) {
    const int j0 = t * 32;
    B8 af[8];                   // A-frags: V^T[o=nt*16+il][jb+j0+qo .. +7], 16B each
#pragma unroll
    for (int nt = 0; nt < 8; ++nt) af[nt].i4 = *(const int4*)(wrow[nt] + j0);
    const int4 aj0 = adjbuf[t & 1][0];
    const int4 aj1 = adjbuf[t & 1][1];
    if (t < 14) {
      adjbuf[t & 1][0] = *(const int4*)(adjq + (t + 2) * 32);
      adjbuf[t & 1][1] = *(const int4*)(adjq + (t + 2) * 32 + 4);
    }
    const float4 d0 = *(const float4*)(dptr + j0);
    const float4 d1 = *(const float4*)(dptr + j0 + 4);
    const float dd[8] = {d0.x, d0.y, d0.z, d0.w, d1.x, d1.y, d1.z, d1.w};
    const int aj[8] = {aj0.x, aj0.y, aj0.z, aj0.w, aj1.x, aj1.y, aj1.z, aj1.w};
    B8 pf;                      // B-frag: P^T[k=j][n=i] == this lane's p for 8 j's
#pragma unroll
    for (int u = 0; u < 8; ++u) {
      float e = sv + dd[u];
      e = fmaxf(e, GAT_ALPHA * e);                 // leaky relu
      float p = __builtin_amdgcn_exp2f(e * LOG2E); // no max-sub needed: e <= ~18
      p = (aj[u] != 0) ? p : 0.f;
      den += p;
      pf.u[u] = f2bf(p);
    }
#pragma unroll
    for (int nt = 0; nt < 8; ++nt)
      acc[nt] = __builtin_amdgcn_mfma_f32_16x16x32_bf16(af[nt].b, pf.b, acc[nt], 0, 0, 0);
  }
  // den partials: sum quads -> every lane holds seg-den for row il
  den += __shfl_xor(den, 16, 64);
  den += __shfl_xor(den, 32, 64);
  if (lane < 16) denb[wave * 16 + il] = den;
  // D layout: col = il = i, row-in-tile = 4*quad + reg = o offset (consecutive o)
#pragma unroll
  for (int nt = 0; nt < 8; ++nt)
    *(f32x4*)(&buf[wave][il][nt * 16 + (quad << 2)]) = acc[nt];
  __syncthreads();
  // combine: wave w handles o-tiles {2w, 2w+1}
  const float dtot = denb[il] + denb[16 + il] + denb[32 + il] + denb[48 + il];
  const float inv = 1.0f / dtot;
  float* op = out + browi * 128;
#pragma unroll
  for (int h = 0; h < 2; ++h) {
    const int nt = wave * 2 + h;
    const int o0 = nt * 16 + (quad << 2);
    f32x4 sum = *(const f32x4*)(&buf[0][il][o0]);
    sum += *(const f32x4*)(&buf[1][il][o0]);
    sum += *(const f32x4*)(&buf[2][il][o0]);
    sum += *(const f32x4*)(&buf[3][il][o0]);
    float4 v;
    v.x = fmaxf(sum[0] * inv, 0.f);
    v.y = fmaxf(sum[1] * inv, 0.f);
    v.z = fmaxf(sum[2] * inv, 0.f);
    v.w = fmaxf(sum[3] * inv, 0.f);
    *(float4*)(op + o0) = v;
  }
}

extern "C" void kernel_launch(void* const* d_in, const int* in_sizes, int n_in,
                              void* d_out, int out_size, void* d_ws, size_t ws_size,
                              hipStream_t stream) {
  const float* x = (const float*)d_in[0];
  const int* adj = (const int*)d_in[1];
  const float* W = (const float*)d_in[2];
  const float* a = (const float*)d_in[3];
  float* out = (float*)d_out;
  // workspace: whT bf16 [8][128][2048] (4 MB) | s fp32 [16384] | d fp32 [16384]
  unsigned short* whT = (unsigned short*)d_ws;
  float* s = (float*)((char*)d_ws + (size_t)8 * 128 * 2048 * 2);
  float* dv = s + 16384;
  gat_wh<<<512, 256, 0, stream>>>(x, W, a, whT, s, dv);
  gat_attn<<<1024, 256, 0, stream>>>(adj, whT, s, dv, out);
}